// Round 6
// baseline (257.546 us; speedup 1.0000x reference)
//
#include <hip/hip_runtime.h>
#include <hip/hip_bf16.h>

#define N_NODES 50000
#define KNB 16
#define FDIM 128
#define HDIM 128
#define ALPHA 0.3f
#define BN_EPS 1e-3f

typedef __bf16 v8bf __attribute__((ext_vector_type(8)));
typedef float v4f __attribute__((ext_vector_type(4)));
typedef unsigned short ushort_t;

__device__ __forceinline__ float blo(unsigned int u) {
    union { float f; unsigned int i; } x; x.i = u << 16; return x.f;
}
__device__ __forceinline__ float bhi(unsigned int u) {
    union { float f; unsigned int i; } x; x.i = u & 0xffff0000u; return x.f;
}

__device__ __forceinline__ unsigned short f2bf(float f) {
    union { float f; unsigned int u; } x;
    x.f = f;
    unsigned int r = x.u + 0x7fffu + ((x.u >> 16) & 1u);  // RNE
    return (unsigned short)(r >> 16);
}

// packed f32x2 -> bf16x2 (RNE)
__device__ __forceinline__ unsigned int pk2(float a, float b) {
    __hip_bfloat162 h = __float22bfloat162_rn(make_float2(a, b));
    union { __hip_bfloat162 h; unsigned int u; } r; r.h = h; return r.u;
}

__device__ __forceinline__ float lrelu(float x) { return x > 0.f ? x : ALPHA * x; }

__device__ __forceinline__ v8bf load8f(const float* p) {
    float4 A = ((const float4*)p)[0];
    float4 B = ((const float4*)p)[1];
    union { v8bf v; unsigned int u[4]; } r;
    r.u[0] = pk2(A.x, A.y); r.u[1] = pk2(A.z, A.w);
    r.u[2] = pk2(B.x, B.y); r.u[3] = pk2(B.z, B.w);
    return r.v;
}

// ---------------------------------------------------------------------------
// Kernel 0: convert + transpose weights to bf16 once.
// WT layout (ushort): [0) WqT 128x128 | [16384) WkT | [32768) WvT | [49152) W1T 128x256
// ---------------------------------------------------------------------------
__global__ __launch_bounds__(256) void prep_kernel(
    const float* __restrict__ Wq, const float* __restrict__ Wk,
    const float* __restrict__ Wv, const float* __restrict__ W1,
    ushort_t* __restrict__ WT)
{
    const int idx = blockIdx.x * 256 + threadIdx.x;
    if (idx < 16384) {
        int k = idx >> 7, n = idx & 127;
        WT[n * 128 + k] = f2bf(Wq[idx]);
    } else if (idx < 32768) {
        int i = idx - 16384; int k = i >> 7, n = i & 127;
        WT[16384 + n * 128 + k] = f2bf(Wk[i]);
    } else if (idx < 49152) {
        int i = idx - 32768; int k = i >> 7, n = i & 127;
        WT[32768 + n * 128 + k] = f2bf(Wv[i]);
    } else if (idx < 81920) {
        int i = idx - 49152; int k = i >> 7, n = i & 127;  // k in [0,256)
        WT[49152 + n * 256 + k] = f2bf(W1[i]);
    }
}

// ---------------------------------------------------------------------------
// Kernel A: Q = lrelu(E@Wq+bq) [f32 -> d_out], K,V -> interleaved KV [bf16].
// BARRIER-FREE / LDS-FREE: B-fragments read directly from global WT (96 KB,
// L2-resident — every block touches the same lines). 782 blocks x 4 waves x
// 16 rows; waves fully independent, pure dataflow.
// ---------------------------------------------------------------------------
__global__ __launch_bounds__(256, 4) void qkv_kernel(
    const float* __restrict__ E, const ushort_t* __restrict__ WT,
    const float* __restrict__ bq, const float* __restrict__ bk,
    const float* __restrict__ bv,
    float* __restrict__ Qo, ushort_t* __restrict__ KV)
{
    const int tid  = threadIdx.x;
    const int wave = tid >> 6;
    const int lane = tid & 63;
    const int quad = lane >> 4;
    const int j    = lane & 15;
    const int row0 = blockIdx.x * 64 + wave * 16;

    const int ar = min(row0 + j, N_NODES - 1);

    // Preload A fragments once (f32 -> bf16), reused for all 3 GEMMs
    v8bf af[4];
#pragma unroll
    for (int ks = 0; ks < 4; ++ks)
        af[ks] = load8f(E + (size_t)ar * FDIM + ks * 32 + quad * 8);

    const float* biases[3] = {bq, bk, bv};

    for (int w = 0; w < 3; ++w) {
        const ushort_t* Wsrc = WT + w * 16384;

        v4f acc[8];
#pragma unroll
        for (int c = 0; c < 8; ++c) acc[c] = (v4f){0.f, 0.f, 0.f, 0.f};

#pragma unroll
        for (int ks = 0; ks < 4; ++ks) {
            const int k0 = ks * 32 + quad * 8;
            v8bf b[8];
#pragma unroll
            for (int c = 0; c < 8; ++c)
                b[c] = *(const v8bf*)(Wsrc + (c * 16 + j) * 128 + k0);
#pragma unroll
            for (int c = 0; c < 8; ++c)
                acc[c] = __builtin_amdgcn_mfma_f32_16x16x32_bf16(af[ks], b[c], acc[c], 0, 0, 0);
        }

        const float* bias = biases[w];
#pragma unroll
        for (int c = 0; c < 8; ++c) {
            const int col = c * 16 + j;
            const float bv_ = bias[col];
#pragma unroll
            for (int i = 0; i < 4; ++i) {
                const int r = row0 + quad * 4 + i;
                if (r < N_NODES) {
                    const float x = lrelu(acc[c][i] + bv_);
                    if (w == 0)      Qo[(size_t)r * HDIM + col] = x;
                    else if (w == 1) KV[(size_t)r * 256 + col] = f2bf(x);        // K half
                    else             KV[(size_t)r * 256 + 128 + col] = f2bf(x);  // V half
                }
            }
        }
    }
}

// ---------------------------------------------------------------------------
// Kernel B: FUSED attention + FFN + norm + BN.
// Block = 64 nodes. Phase 1: each wave pools 16 of the block's nodes
// (round-3-style wave-uniform gathers — empirically fastest) into LDS (bf16,
// stride 136: conflict-free dword writes, 2-way-free b128 reads).
// Phase 2: out = BN(rownorm(lrelu([E,pooled]@W1+b1))), A-half1 from LDS,
// B-frags direct from global W1T (64 KB, L2-resident). Out overwrites Q rows
// this block owns (cross-block disjoint; in-block ordered by the barrier).
// ---------------------------------------------------------------------------
__global__ __launch_bounds__(256, 4) void attn_out_kernel(
    const float* __restrict__ Q,          // d_out (f32), also final Out
    const ushort_t* __restrict__ KV,
    const float* __restrict__ E, const ushort_t* __restrict__ W1T,
    const int* __restrict__ nbr,
    const float* __restrict__ b1,
    const float* __restrict__ gamma, const float* __restrict__ beta,
    const float* __restrict__ mmean, const float* __restrict__ mvar,
    float* __restrict__ Out)
{
    __shared__ ushort_t sPool[64 * 136];   // pooled, bf16, padded stride

    const int tid  = threadIdx.x;
    const int wave = tid >> 6;
    const int lane = tid & 63;
    const int quad = lane >> 4;
    const int j    = lane & 15;
    const int row0b = blockIdx.x * 64;

    // ---- Phase 1: attention pooling for this wave's 16 nodes ----
    for (int i = 0; i < 16; ++i) {
        const int nl = wave * 16 + i;
        const int node = row0b + nl;                  // wave-uniform
        if (node < N_NODES) {
            const float2 qp = ((const float2*)(Q + (size_t)node * HDIM))[lane];
            const int* nb = nbr + node * KNB;

            int ids[KNB];
#pragma unroll
            for (int t = 0; t < KNB; ++t) {
                int id = nb[t];
                ids[t] = ((unsigned)id < (unsigned)N_NODES) ? id : 0;
            }

            float sc[KNB];
#pragma unroll
            for (int t = 0; t < KNB; ++t) {
                const unsigned int kp = ((const unsigned int*)(KV + (size_t)ids[t] * 256))[lane];
                float p = qp.x * blo(kp) + qp.y * bhi(kp);
                p += __shfl_xor(p, 32, 64);
                p += __shfl_xor(p, 16, 64);
                p += __shfl_xor(p, 8, 64);
                p += __shfl_xor(p, 4, 64);
                p += __shfl_xor(p, 2, 64);
                p += __shfl_xor(p, 1, 64);
                sc[t] = p;                            // wave-uniform
            }

            float m = sc[0];
#pragma unroll
            for (int t = 1; t < KNB; ++t) m = fmaxf(m, sc[t]);
            float sum = 0.f;
#pragma unroll
            for (int t = 0; t < KNB; ++t) { sc[t] = __expf(sc[t] - m); sum += sc[t]; }
            const float inv = 1.f / sum;

            float p0 = 0.f, p1 = 0.f;
#pragma unroll
            for (int t = 0; t < KNB; ++t) {
                const unsigned int vp =
                    ((const unsigned int*)(KV + (size_t)ids[t] * 256 + 128))[lane];
                p0 += sc[t] * blo(vp);
                p1 += sc[t] * bhi(vp);
            }
            *(unsigned int*)(&sPool[nl * 136 + 2 * lane]) = pk2(p0 * inv, p1 * inv);
        } else {
            *(unsigned int*)(&sPool[nl * 136 + 2 * lane]) = 0u;
        }
    }

    __syncthreads();

    // ---- Phase 2: FFN GEMM + fused epilogue for this wave's 16 rows ----
    const int row0 = row0b + wave * 16;
    const int ar = min(row0 + j, N_NODES - 1);

    v4f acc[8];
#pragma unroll
    for (int c = 0; c < 8; ++c) acc[c] = (v4f){0.f, 0.f, 0.f, 0.f};

    // half 0: A from E (k = 0..127)
#pragma unroll
    for (int ks = 0; ks < 4; ++ks) {
        const int k0 = ks * 32 + quad * 8;
        v8bf a = load8f(E + (size_t)ar * 128 + k0);
        v8bf b[8];
#pragma unroll
        for (int c = 0; c < 8; ++c)
            b[c] = *(const v8bf*)(W1T + (c * 16 + j) * 256 + k0);
#pragma unroll
        for (int c = 0; c < 8; ++c)
            acc[c] = __builtin_amdgcn_mfma_f32_16x16x32_bf16(a, b[c], acc[c], 0, 0, 0);
    }
    // half 1: A from LDS pooled (k = 128..255)
#pragma unroll
    for (int ks = 0; ks < 4; ++ks) {
        const int k0 = ks * 32 + quad * 8;
        v8bf a = *(const v8bf*)(&sPool[(wave * 16 + j) * 136 + k0]);
        v8bf b[8];
#pragma unroll
        for (int c = 0; c < 8; ++c)
            b[c] = *(const v8bf*)(W1T + (c * 16 + j) * 256 + 128 + k0);
#pragma unroll
        for (int c = 0; c < 8; ++c)
            acc[c] = __builtin_amdgcn_mfma_f32_16x16x32_bf16(a, b[c], acc[c], 0, 0, 0);
    }

    float scale_[8], shift_[8], bias_[8];
#pragma unroll
    for (int c = 0; c < 8; ++c) {
        const int col = c * 16 + j;
        const float sc = gamma[col] * rsqrtf(mvar[col] + BN_EPS);
        scale_[c] = sc;
        shift_[c] = beta[col] - mmean[col] * sc;
        bias_[c]  = b1[col];
    }

#pragma unroll
    for (int c = 0; c < 8; ++c)
#pragma unroll
        for (int i = 0; i < 4; ++i)
            acc[c][i] = lrelu(acc[c][i] + bias_[c]);

#pragma unroll
    for (int i = 0; i < 4; ++i) {
        float ss = 0.f;
#pragma unroll
        for (int c = 0; c < 8; ++c) ss += acc[c][i] * acc[c][i];
        ss += __shfl_xor(ss, 1, 64);
        ss += __shfl_xor(ss, 2, 64);
        ss += __shfl_xor(ss, 4, 64);
        ss += __shfl_xor(ss, 8, 64);
        const float invn = 1.f / (sqrtf(ss) + 1e-6f);
        const int r = row0 + quad * 4 + i;
        if (r < N_NODES) {
#pragma unroll
            for (int c = 0; c < 8; ++c)
                Out[(size_t)r * HDIM + c * 16 + j] =
                    acc[c][i] * invn * scale_[c] + shift_[c];
        }
    }
}

extern "C" void kernel_launch(void* const* d_in, const int* in_sizes, int n_in,
                              void* d_out, int out_size, void* d_ws, size_t ws_size,
                              hipStream_t stream)
{
    const float* E     = (const float*)d_in[0];
    const int*   nbr   = (const int*)d_in[2];
    const float* Wq    = (const float*)d_in[3];
    const float* bq    = (const float*)d_in[4];
    const float* Wk    = (const float*)d_in[5];
    const float* bk    = (const float*)d_in[6];
    const float* Wv    = (const float*)d_in[7];
    const float* bv    = (const float*)d_in[8];
    const float* W1    = (const float*)d_in[9];
    const float* b1    = (const float*)d_in[10];
    const float* gam   = (const float*)d_in[11];
    const float* bet   = (const float*)d_in[12];
    const float* mmean = (const float*)d_in[13];
    const float* mvar  = (const float*)d_in[14];

    // ws: KV interleaved bf16 (25.6 MB) + WT bf16 (160 KB).
    // Q (f32) lives in d_out, overwritten in place by the final output.
    ushort_t* KV = (ushort_t*)d_ws;
    ushort_t* WT = KV + (size_t)N_NODES * 256;
    float* QP = (float*)d_out;

    const int gridA = (N_NODES + 63) / 64;  // 782
    prep_kernel<<<320, 256, 0, stream>>>(Wq, Wk, Wv, W1, WT);
    qkv_kernel<<<gridA, 256, 0, stream>>>(E, WT, bq, bk, bv, QP, KV);
    attn_out_kernel<<<gridA, 256, 0, stream>>>(QP, KV, E, WT + 49152, nbr,
                                               b1, gam, bet, mmean, mvar, QP);
}

// Round 8
// 220.900 us; speedup vs baseline: 1.1659x; 1.1659x over previous
//
#include <hip/hip_runtime.h>
#include <hip/hip_bf16.h>

#define N_NODES 50000
#define KNB 16
#define FDIM 128
#define HDIM 128
#define ALPHA 0.3f
#define BN_EPS 1e-3f

typedef __bf16 v8bf __attribute__((ext_vector_type(8)));
typedef float v4f __attribute__((ext_vector_type(4)));
typedef unsigned short ushort_t;

__device__ __forceinline__ float blo(unsigned int u) {
    union { float f; unsigned int i; } x; x.i = u << 16; return x.f;
}
__device__ __forceinline__ float bhi(unsigned int u) {
    union { float f; unsigned int i; } x; x.i = u & 0xffff0000u; return x.f;
}

__device__ __forceinline__ unsigned short f2bf(float f) {
    union { float f; unsigned int u; } x;
    x.f = f;
    unsigned int r = x.u + 0x7fffu + ((x.u >> 16) & 1u);  // RNE
    return (unsigned short)(r >> 16);
}

// packed f32x2 -> bf16x2 (RNE)
__device__ __forceinline__ unsigned int pk2(float a, float b) {
    __hip_bfloat162 h = __float22bfloat162_rn(make_float2(a, b));
    union { __hip_bfloat162 h; unsigned int u; } r; r.h = h; return r.u;
}

__device__ __forceinline__ float lrelu(float x) { return x > 0.f ? x : ALPHA * x; }

__device__ __forceinline__ v8bf load8f(const float* p) {
    float4 A = ((const float4*)p)[0];
    float4 B = ((const float4*)p)[1];
    union { v8bf v; unsigned int u[4]; } r;
    r.u[0] = pk2(A.x, A.y); r.u[1] = pk2(A.z, A.w);
    r.u[2] = pk2(B.x, B.y); r.u[3] = pk2(B.z, B.w);
    return r.v;
}

// ---------------------------------------------------------------------------
// Kernel 0: convert + transpose weights to bf16 once.
// WT layout (ushort): [0) WqT 128x128 | [16384) WkT | [32768) WvT | [49152) W1T 128x256
// ---------------------------------------------------------------------------
__global__ __launch_bounds__(256) void prep_kernel(
    const float* __restrict__ Wq, const float* __restrict__ Wk,
    const float* __restrict__ Wv, const float* __restrict__ W1,
    ushort_t* __restrict__ WT)
{
    const int idx = blockIdx.x * 256 + threadIdx.x;
    if (idx < 16384) {
        int k = idx >> 7, n = idx & 127;
        WT[n * 128 + k] = f2bf(Wq[idx]);
    } else if (idx < 32768) {
        int i = idx - 16384; int k = i >> 7, n = i & 127;
        WT[16384 + n * 128 + k] = f2bf(Wk[i]);
    } else if (idx < 49152) {
        int i = idx - 32768; int k = i >> 7, n = i & 127;
        WT[32768 + n * 128 + k] = f2bf(Wv[i]);
    } else if (idx < 81920) {
        int i = idx - 49152; int k = i >> 7, n = i & 127;  // k in [0,256)
        WT[49152 + n * 256 + k] = f2bf(W1[i]);
    }
}

// ---------------------------------------------------------------------------
// Kernel A: Q = lrelu(E@Wq+bq) [f32 -> d_out], K,V -> interleaved KV [bf16].
// 128-row tiles (391 blocks), wave = 32 rows. A-frags loaded+converted ONCE,
// reused across 3 GEMMs. B staged in LDS (stride 136, conflict-free b128).
// ---------------------------------------------------------------------------
__global__ __launch_bounds__(256) void qkv_kernel(
    const float* __restrict__ E, const ushort_t* __restrict__ WT,
    const float* __restrict__ bq, const float* __restrict__ bk,
    const float* __restrict__ bv,
    float* __restrict__ Qo, ushort_t* __restrict__ KV)
{
    __shared__ ushort_t sW[128 * 136];

    const int tid  = threadIdx.x;
    const int wave = tid >> 6;
    const int lane = tid & 63;
    const int quad = lane >> 4;
    const int j    = lane & 15;
    const int row0 = blockIdx.x * 128 + wave * 32;

    const int ar0 = min(row0 + j,      N_NODES - 1);
    const int ar1 = min(row0 + 16 + j, N_NODES - 1);

    v8bf a0f[4], a1f[4];
#pragma unroll
    for (int ks = 0; ks < 4; ++ks) {
        const int k0 = ks * 32 + quad * 8;
        a0f[ks] = load8f(E + (size_t)ar0 * FDIM + k0);
        a1f[ks] = load8f(E + (size_t)ar1 * FDIM + k0);
    }

    const float* biases[3] = {bq, bk, bv};

    for (int w = 0; w < 3; ++w) {
        const ushort_t* Wsrc = WT + w * 16384;
        for (int i = tid; i < 2048; i += 256) {         // 16B copies
            int n = i >> 4, kc = i & 15;
            *(uint4*)(&sW[n * 136 + kc * 8]) = *(const uint4*)(Wsrc + n * 128 + kc * 8);
        }
        __syncthreads();

        v4f acc[2][8];
#pragma unroll
        for (int rb = 0; rb < 2; ++rb)
#pragma unroll
            for (int c = 0; c < 8; ++c) acc[rb][c] = (v4f){0.f, 0.f, 0.f, 0.f};

#pragma unroll
        for (int ks = 0; ks < 4; ++ks) {
            const int k0 = ks * 32 + quad * 8;
            v8bf b[8];
#pragma unroll
            for (int c = 0; c < 8; ++c)
                b[c] = *(const v8bf*)(&sW[(c * 16 + j) * 136 + k0]);
#pragma unroll
            for (int c = 0; c < 8; ++c) {
                acc[0][c] = __builtin_amdgcn_mfma_f32_16x16x32_bf16(a0f[ks], b[c], acc[0][c], 0, 0, 0);
                acc[1][c] = __builtin_amdgcn_mfma_f32_16x16x32_bf16(a1f[ks], b[c], acc[1][c], 0, 0, 0);
            }
        }

        const float* bias = biases[w];
#pragma unroll
        for (int c = 0; c < 8; ++c) {
            const int col = c * 16 + j;
            const float bv_ = bias[col];
#pragma unroll
            for (int rb = 0; rb < 2; ++rb) {
#pragma unroll
                for (int i = 0; i < 4; ++i) {
                    const int r = row0 + rb * 16 + quad * 4 + i;
                    if (r < N_NODES) {
                        const float x = lrelu(acc[rb][c][i] + bv_);
                        if (w == 0)      Qo[(size_t)r * HDIM + col] = x;
                        else if (w == 1) KV[(size_t)r * 256 + col] = f2bf(x);        // K half
                        else             KV[(size_t)r * 256 + 128 + col] = f2bf(x);  // V half
                    }
                }
            }
        }
        __syncthreads();
    }
}

// ---------------------------------------------------------------------------
// Kernel B (R3/R4-proven): one wave per node, 4 nodes/block, 12500 blocks.
// Reads q (f32) from QP[node], overwrites the same row with pooled (f32) —
// same-wave read-before-write, safe. No LDS, no barriers.
// ---------------------------------------------------------------------------
__global__ __launch_bounds__(256) void attn_kernel(
    float* __restrict__ QP, const ushort_t* __restrict__ KV,
    const int* __restrict__ nbr)
{
    const int tid  = threadIdx.x;
    const int wave = tid >> 6;
    const int lane = tid & 63;
    const int node = __builtin_amdgcn_readfirstlane(blockIdx.x * 4 + wave);

    const float2 qp = ((const float2*)(QP + (size_t)node * HDIM))[lane];

    int idxs[KNB];
    const int* nb = nbr + node * KNB;   // uniform base -> scalar loads
#pragma unroll
    for (int t = 0; t < KNB; ++t) {
        int id = nb[t];
        idxs[t] = ((unsigned)id < (unsigned)N_NODES) ? id : 0;
    }

    float sc[KNB];
#pragma unroll
    for (int t = 0; t < KNB; ++t) {
        const unsigned int kp = ((const unsigned int*)(KV + (size_t)idxs[t] * 256))[lane];
        float p = qp.x * blo(kp) + qp.y * bhi(kp);
#pragma unroll
        for (int off = 32; off >= 1; off >>= 1) p += __shfl_xor(p, off, 64);
        sc[t] = p;
    }

    float m = sc[0];
#pragma unroll
    for (int t = 1; t < KNB; ++t) m = fmaxf(m, sc[t]);
    float s = 0.f;
#pragma unroll
    for (int t = 0; t < KNB; ++t) { sc[t] = __expf(sc[t] - m); s += sc[t]; }
    const float inv = 1.f / s;

    float p0 = 0.f, p1 = 0.f;
#pragma unroll
    for (int t = 0; t < KNB; ++t) {
        const unsigned int vp = ((const unsigned int*)(KV + (size_t)idxs[t] * 256 + 128))[lane];
        const float a = sc[t] * inv;
        p0 += a * blo(vp);
        p1 += a * bhi(vp);
    }

    ((float2*)(QP + (size_t)node * HDIM))[lane] = make_float2(p0, p1);
}

// ---------------------------------------------------------------------------
// Kernel C (R4-proven aliasing): out = BN(rownorm(lrelu([E,pooled]@W1+b1))).
// pooled (f32) lives in d_out; result overwrites d_out. The barrier at the
// end of half=1 orders all pooled reads before any epilogue write within a
// block; blocks read/write only their own row range (clamped reads in block
// 390 target its own rows) — no cross-block hazard.
// ---------------------------------------------------------------------------
__global__ __launch_bounds__(256) void out_kernel(
    const float* __restrict__ E, const ushort_t* __restrict__ W1T,
    const float* __restrict__ b1,
    const float* __restrict__ gamma, const float* __restrict__ beta,
    const float* __restrict__ mmean, const float* __restrict__ mvar,
    float* __restrict__ OutP)   // pooled (in) + out (result)
{
    __shared__ ushort_t sW[128 * 136];

    const int tid  = threadIdx.x;
    const int wave = tid >> 6;
    const int lane = tid & 63;
    const int quad = lane >> 4;
    const int j    = lane & 15;
    const int row0 = blockIdx.x * 128 + wave * 32;

    const int ar0 = min(row0 + j,      N_NODES - 1);
    const int ar1 = min(row0 + 16 + j, N_NODES - 1);

    v4f acc[2][8];
#pragma unroll
    for (int rb = 0; rb < 2; ++rb)
#pragma unroll
        for (int c = 0; c < 8; ++c) acc[rb][c] = (v4f){0.f, 0.f, 0.f, 0.f};

    for (int half = 0; half < 2; ++half) {
        for (int i = tid; i < 2048; i += 256) {
            int n = i >> 4, kc = i & 15;
            *(uint4*)(&sW[n * 136 + kc * 8]) =
                *(const uint4*)(W1T + n * 256 + half * 128 + kc * 8);
        }
        __syncthreads();

        const float* Abase = (half == 0) ? E : (const float*)OutP;
#pragma unroll
        for (int ks = 0; ks < 4; ++ks) {
            const int k0 = ks * 32 + quad * 8;
            v8bf a0 = load8f(Abase + (size_t)ar0 * 128 + k0);
            v8bf a1 = load8f(Abase + (size_t)ar1 * 128 + k0);
            v8bf b[8];
#pragma unroll
            for (int c = 0; c < 8; ++c)
                b[c] = *(const v8bf*)(&sW[(c * 16 + j) * 136 + k0]);
#pragma unroll
            for (int c = 0; c < 8; ++c) {
                acc[0][c] = __builtin_amdgcn_mfma_f32_16x16x32_bf16(a0, b[c], acc[0][c], 0, 0, 0);
                acc[1][c] = __builtin_amdgcn_mfma_f32_16x16x32_bf16(a1, b[c], acc[1][c], 0, 0, 0);
            }
        }
        __syncthreads();   // orders pooled reads before epilogue writes
    }

    float scale_[8], shift_[8], bias_[8];
#pragma unroll
    for (int c = 0; c < 8; ++c) {
        const int col = c * 16 + j;
        const float sc = gamma[col] * rsqrtf(mvar[col] + BN_EPS);
        scale_[c] = sc;
        shift_[c] = beta[col] - mmean[col] * sc;
        bias_[c]  = b1[col];
    }

#pragma unroll
    for (int rb = 0; rb < 2; ++rb)
#pragma unroll
        for (int c = 0; c < 8; ++c)
#pragma unroll
            for (int i = 0; i < 4; ++i)
                acc[rb][c][i] = lrelu(acc[rb][c][i] + bias_[c]);

#pragma unroll
    for (int rb = 0; rb < 2; ++rb) {
#pragma unroll
        for (int i = 0; i < 4; ++i) {
            float ss = 0.f;
#pragma unroll
            for (int c = 0; c < 8; ++c) ss += acc[rb][c][i] * acc[rb][c][i];
            ss += __shfl_xor(ss, 1, 64);
            ss += __shfl_xor(ss, 2, 64);
            ss += __shfl_xor(ss, 4, 64);
            ss += __shfl_xor(ss, 8, 64);
            const float invn = 1.f / (sqrtf(ss) + 1e-6f);
            const int r = row0 + rb * 16 + quad * 4 + i;
            if (r < N_NODES) {
#pragma unroll
                for (int c = 0; c < 8; ++c)
                    OutP[(size_t)r * HDIM + c * 16 + j] =
                        acc[rb][c][i] * invn * scale_[c] + shift_[c];
            }
        }
    }
}

extern "C" void kernel_launch(void* const* d_in, const int* in_sizes, int n_in,
                              void* d_out, int out_size, void* d_ws, size_t ws_size,
                              hipStream_t stream)
{
    const float* E     = (const float*)d_in[0];
    const int*   nbr   = (const int*)d_in[2];
    const float* Wq    = (const float*)d_in[3];
    const float* bq    = (const float*)d_in[4];
    const float* Wk    = (const float*)d_in[5];
    const float* bk    = (const float*)d_in[6];
    const float* Wv    = (const float*)d_in[7];
    const float* bv    = (const float*)d_in[8];
    const float* W1    = (const float*)d_in[9];
    const float* b1    = (const float*)d_in[10];
    const float* gam   = (const float*)d_in[11];
    const float* bet   = (const float*)d_in[12];
    const float* mmean = (const float*)d_in[13];
    const float* mvar  = (const float*)d_in[14];

    // ws: KV interleaved bf16 (25.6 MB) + WT bf16 (160 KB) = 25.76 MB total
    // (PROVEN budget — R7's 38.56 MB overflowed d_ws and corrupted the
    // harness's pristine buffers). Q (f32) then pooled (f32) share d_out.
    ushort_t* KV = (ushort_t*)d_ws;
    ushort_t* WT = KV + (size_t)N_NODES * 256;
    float* QP = (float*)d_out;

    const int gridA = (N_NODES + 127) / 128;  // 391
    prep_kernel<<<320, 256, 0, stream>>>(Wq, Wk, Wv, W1, WT);
    qkv_kernel<<<gridA, 256, 0, stream>>>(E, WT, bq, bk, bv, QP, KV);
    attn_kernel<<<N_NODES / 4, 256, 0, stream>>>(QP, KV, nbr);
    out_kernel<<<gridA, 256, 0, stream>>>(E, WT + 49152, b1, gam, bet, mmean, mvar, QP);
}